// Round 16
// baseline (430.986 us; speedup 1.0000x reference)
//
#include <hip/hip_runtime.h>
#include <hip/hip_bf16.h>

// VQ-VAE EMA vector quantizer, MI355X — round 16:
//  * argmin v9: K-SPLIT. Grid (512 point-blocks x 2 codebook halves) = 1024
//    blocks -> 4 blocks/CU, 16 waves/CU (r13/r15 were grid-capped at 8
//    waves/CU: 2048 waves fixed by 32-points-per-wave). Each half tracks its
//    exact top-2 into deterministic float4 slots; merge kernel combines
//    (exact same values+order => identical idx/flags/absmax=752).
//  * Single-buffer 32KB LDS tile (r15-proven), 108 VGPR.
//  * Rest identical to r13/r15's proven structure. 8 dispatches.
// Outputs (flat f32): z_q_st | idx-as-float | loss | new_codebook | new_ema_count | new_ema_weight

#define KC 2048
#define DD 256
#define NB 16
#define HWS 4096
#define NPTS 65536
#define DECAYF 0.99f
#define ONEMD 0.01f
#define EPSF 1e-5f
#define NCH 2
#define MARGIN 0.0625f
#define CHPTS 32
#define FPT 64
#define NLOSS 4096

typedef __attribute__((ext_vector_type(8))) short short8v;
typedef __attribute__((ext_vector_type(16))) float f32x16;

// ---- workspace layout (bytes) — identical to r7..r15 (74219776) ----
#define WS_IDX     0                          // int32 [65536]
#define WS_SORTED  262144                     // int32 [65536]
#define WS_CNTI    524288                     // int32 [2048]   (zeroed in prep)
#define WS_START   532480                     // int32 [2048]
#define WS_CURSOR  540672                     // int32 [2048]
#define WS_FLAGCNT 548864                     // int32 [1]      (zeroed in prep)
#define WS_FLAGS   549120                     // int32 [65536]
#define WS_LOSSP   549120                     // f32 [4096] overlay (written after flags dead)
#define WS_CNORM   811264                     // f32 [2048]
#define WS_PART    819456                     // fixmin u64[65536] (init in merge) / dwacc f32[KC*DD] (zeroed in zq tail)
#define WS_HALF    2916352                    // float4 [131072] per-(point,half) top-2 results, 2 MB (dead after merge)
#define WS_CBH     5013760                    // bf16 [2048*256] fragment order, 1 MB
#define WS_CBL     6062336                    // bf16 [2048*256] fragment order, 1 MB
#define WS_ZH      7110912                    // bf16 [65536*256] 32 MB
#define WS_ZL      40665344                   // bf16 [65536*256] 32 MB
#define WS_NEED_MFMA 74219776ULL
#define WS_NEED_MID  5013760ULL

// ---- output offsets (floats) ----
#define OUT_ZQ   0
#define OUT_IDX  16777216
#define OUT_LOSS (OUT_IDX + NPTS)
#define OUT_CB   (OUT_LOSS + 1)
#define OUT_CNT  (OUT_CB + KC*DD)
#define OUT_W    (OUT_CNT + KC)

// ---------------------------------------------------------------------------
static __device__ __forceinline__ unsigned short f2bf_rn(float x) {
    unsigned u = __builtin_bit_cast(unsigned, x);
    unsigned r = (u + 0x7FFFu + ((u >> 16) & 1u)) >> 16;
    return (unsigned short)r;
}
static __device__ __forceinline__ float bf2f(unsigned short h) {
    unsigned u = ((unsigned)h) << 16;
    return __builtin_bit_cast(float, u);
}
static __device__ __forceinline__ void gload_lds16(const unsigned short* g,
                                                   unsigned short* l) {
    __builtin_amdgcn_global_load_lds(
        (const __attribute__((address_space(1))) void*)g,
        (__attribute__((address_space(3))) void*)l, 16, 0, 0);
}

// ---------------------------------------------------------------------------
// prep = transpose (blocks 0..4095) + cbsplit (blocks 4096..4103, zeroes
// cnti + flagcnt).
__global__ __launch_bounds__(256) void prep_kernel(const float* __restrict__ z_e,
                                                   const float* __restrict__ cb,
                                                   float* __restrict__ cnorm,
                                                   unsigned short* __restrict__ cbs_h,
                                                   unsigned short* __restrict__ cbs_l,
                                                   unsigned short* __restrict__ zh,
                                                   unsigned short* __restrict__ zl,
                                                   int* __restrict__ cnti,
                                                   int* __restrict__ flagcnt) {
    const int tid = threadIdx.x;
    if (blockIdx.x >= 4096) {
        int k = (blockIdx.x - 4096) * 256 + tid;
        cnti[k] = 0;
        if (k == 0) *flagcnt = 0;
        const int ct = k >> 5, lc = k & 31;
        const float4* row = reinterpret_cast<const float4*>(cb + (size_t)k * DD);
        float s = 0.f;
        #pragma unroll 4
        for (int chunk = 0; chunk < 32; ++chunk) {
            float4 v0 = row[chunk * 2], v1 = row[chunk * 2 + 1];
            float v[8] = {v0.x, v0.y, v0.z, v0.w, v1.x, v1.y, v1.z, v1.w};
            unsigned short hh[8], ll[8];
            #pragma unroll
            for (int j = 0; j < 8; ++j) {
                s += v[j] * v[j];
                hh[j] = f2bf_rn(v[j]);
                ll[j] = f2bf_rn(v[j] - bf2f(hh[j]));
            }
            const int ks = chunk >> 1, h = chunk & 1;
            size_t dst = (size_t)ct * 8192 + ks * 512 + (h * 32 + lc) * 8;
            *reinterpret_cast<ushort4*>(cbs_h + dst)     = *(ushort4*)&hh[0];
            *reinterpret_cast<ushort4*>(cbs_h + dst + 4) = *(ushort4*)&hh[4];
            *reinterpret_cast<ushort4*>(cbs_l + dst)     = *(ushort4*)&ll[0];
            *reinterpret_cast<ushort4*>(cbs_l + dst + 4) = *(ushort4*)&ll[4];
        }
        cnorm[k] = s;
        return;
    }
    __shared__ float t_lds[64][65];
    const int bid = blockIdx.x;
    const int hw0 = (bid & 63) * 64;
    const int d0 = ((bid >> 6) & 3) * 64;
    const int b = bid >> 8;
    const float* src = z_e + (size_t)b * DD * HWS;
    #pragma unroll
    for (int i = 0; i < 16; ++i) {
        int li = tid + i * 256;
        int d = li >> 6, hw = li & 63;
        t_lds[d][hw] = src[(size_t)(d0 + d) * HWS + hw0 + hw];
    }
    __syncthreads();
    #pragma unroll
    for (int i = 0; i < 16; ++i) {
        int li = tid + i * 256;
        int p = li >> 6, d = li & 63;
        float x = t_lds[d][p];
        unsigned short h = f2bf_rn(x);
        unsigned short l = f2bf_rn(x - bf2f(h));
        size_t o = ((size_t)b * HWS + hw0 + p) * DD + d0 + d;
        zh[o] = h; zl[o] = l;
    }
}

// fp32-cnorm only (fallback tier)
__global__ __launch_bounds__(256) void cnorm_kernel(const float* __restrict__ cb,
                                                    float* __restrict__ cnorm) {
    int k = blockIdx.x * 256 + threadIdx.x;
    if (k < KC) {
        const float4* row = reinterpret_cast<const float4*>(cb + (size_t)k * DD);
        float s = 0.f;
        #pragma unroll 8
        for (int i = 0; i < DD / 4; ++i) {
            float4 v = row[i];
            s += v.x * v.x + v.y * v.y + v.z * v.z + v.w * v.w;
        }
        cnorm[k] = s;
    }
}

// ---------------------------------------------------------------------------
// MFMA argmin v9: grid (512, 2). Block = 128 points x half the codebook
// (1024 codes, 32 tiles). Single-buffer 32KB LDS tile; 3 MFMA chains.
// Per-half exact top-2 -> halfres[p*2+khalf] (deterministic slot, no atomics).
__global__ __launch_bounds__(256, 2) void argmin_mfma_kernel(const unsigned short* __restrict__ zh,
                                                             const unsigned short* __restrict__ zl,
                                                             const unsigned short* __restrict__ cbs_h,
                                                             const unsigned short* __restrict__ cbs_l,
                                                             const float* __restrict__ cnorm,
                                                             float4* __restrict__ halfres) {
    __shared__ unsigned short lds_cb[2][16][512];   // [hi/lo][ks][64 lanes * 8] = 32 KB

    const int tid = threadIdx.x;
    const int w = tid >> 6, lane = tid & 63;
    const int lc = lane & 31, h = lane >> 5;
    const int p = blockIdx.x * 128 + w * 32 + lc;
    const int khalf = blockIdx.y;
    const int ct0 = khalf * (KC / 64);              // 32 tiles per half

    const short8v* zhp = reinterpret_cast<const short8v*>(zh + (size_t)p * DD + h * 8);
    const short8v* zlp = reinterpret_cast<const short8v*>(zl + (size_t)p * DD + h * 8);
    short8v bh[16], bl[16];
    #pragma unroll
    for (int ks = 0; ks < 16; ++ks) { bh[ks] = zhp[ks * 2]; bl[ks] = zlp[ks * 2]; }

    auto stage = [&](int ct) {
        #pragma unroll
        for (int j = 0; j < 8; ++j) {
            const int inst = w * 8 + j;          // 0..31
            const int part = inst >> 4;          // 0=hi 1=lo
            const int ks = inst & 15;
            const unsigned short* src =
                (part ? cbs_l : cbs_h) + (size_t)ct * 8192 + ks * 512 + lane * 8;
            gload_lds16(src, &lds_cb[part][ks][0]);
        }
    };

    float bv1 = 3.4e38f, bv2 = 3.4e38f;
    int bi1 = khalf * (KC / 2);

    stage(ct0);
    __syncthreads();

    for (int ct = ct0; ct < ct0 + KC / 64; ++ct) {
        f32x16 a0, a1, a2;
        #pragma unroll
        for (int i = 0; i < 16; ++i) { a0[i] = 0.f; a1[i] = 0.f; a2[i] = 0.f; }
        #pragma unroll
        for (int ks = 0; ks < 16; ++ks) {
            short8v ah = *reinterpret_cast<const short8v*>(&lds_cb[0][ks][lane * 8]);
            short8v al = *reinterpret_cast<const short8v*>(&lds_cb[1][ks][lane * 8]);
            a0 = __builtin_amdgcn_mfma_f32_32x32x16_bf16(ah, bh[ks], a0, 0, 0, 0);
            a1 = __builtin_amdgcn_mfma_f32_32x32x16_bf16(ah, bl[ks], a1, 0, 0, 0);
            a2 = __builtin_amdgcn_mfma_f32_32x32x16_bf16(al, bh[ks], a2, 0, 0, 0);
        }
        // C layout (32x32): point = lane&31, code_row = (reg&3) + 8*(reg>>2) + 4*h
        const float* cnb = cnorm + ct * 32 + h * 4;
        #pragma unroll
        for (int g = 0; g < 4; ++g) {
            float4 cn = *reinterpret_cast<const float4*>(cnb + g * 8);
            float cna[4] = {cn.x, cn.y, cn.z, cn.w};
            #pragma unroll
            for (int q = 0; q < 4; ++q) {
                float dot = a0[g * 4 + q] + a1[g * 4 + q] + a2[g * 4 + q];
                float v = fmaf(dot, -2.0f, cna[q]);
                int k = ct * 32 + g * 8 + h * 4 + q;
                bool lt = v < bv1;
                bv2 = fminf(bv2, fmaxf(v, bv1));
                bv1 = fminf(bv1, v);
                bi1 = lt ? k : bi1;
            }
        }
        __syncthreads();                 // all waves done reading this tile
        if (ct + 1 < ct0 + KC / 64) {
            stage(ct + 1);
            __syncthreads();             // staging complete before compute
        }
    }

    // merge the two half-wave code-row sets (exact top-2 within this K-half)
    float ov1 = __shfl_xor(bv1, 32, 64);
    float ov2 = __shfl_xor(bv2, 32, 64);
    int   oi1 = __shfl_xor(bi1, 32, 64);
    float nv1 = fminf(bv1, ov1);
    float nv2 = fminf(fmaxf(bv1, ov1), fminf(bv2, ov2));
    int ni1 = (ov1 < bv1 || (ov1 == bv1 && oi1 < bi1)) ? oi1 : bi1;

    if (h == 0) {
        float4 r;
        r.x = nv1; r.y = nv2; r.z = __int_as_float(ni1); r.w = 0.f;
        halfres[(size_t)p * 2 + khalf] = r;
    }
}

// ---------------------------------------------------------------------------
// merge halves: exact global top-2; first-min semantics (half0 idx < half1 idx,
// tie keeps half0). Writes idx + hist + flag + fixmin init.
__global__ __launch_bounds__(256) void merge_kernel(const float4* __restrict__ halfres,
                                                    int* __restrict__ idx_out,
                                                    int* __restrict__ cnti,
                                                    int* __restrict__ flagcnt,
                                                    int* __restrict__ flaglist,
                                                    unsigned long long* __restrict__ fixmin) {
    const int n = blockIdx.x * 256 + threadIdx.x;
    float4 h0 = halfres[(size_t)n * 2];
    float4 h1 = halfres[(size_t)n * 2 + 1];
    const float b0 = h0.x, r0 = h0.y;
    const float b1 = h1.x, r1 = h1.y;
    const int i0 = __float_as_int(h0.z), i1 = __float_as_int(h1.z);

    const float nv1 = fminf(b0, b1);
    const float nv2 = fminf(fmaxf(b0, b1), fminf(r0, r1));
    const int ni1 = (b1 < b0) ? i1 : i0;    // tie -> half0 (lower idx) = first-min

    idx_out[n] = ni1;
    atomicAdd(&cnti[ni1], 1);
    if (nv2 - nv1 < MARGIN) {
        int pos = atomicAdd(flagcnt, 1);
        flaglist[pos] = n;
        fixmin[pos] = ~0ULL;
    }
}

// ---------------------------------------------------------------------------
// fixup stage 1: grid-stride (x over 64-point chunks, y over 64-code tiles);
// exact fp32; packed u64 atomicMin == exact first-min semantics.
__global__ __launch_bounds__(256) void fixup_part_kernel(const float* __restrict__ z_e,
                                                         const float* __restrict__ cb,
                                                         const float* __restrict__ cnorm,
                                                         const int* __restrict__ flagcnt,
                                                         const int* __restrict__ flaglist,
                                                         unsigned long long* __restrict__ fixmin) {
    __shared__ float As[64][FPT + 4];
    __shared__ float Bs[64][64 + 4];
    __shared__ float rv[FPT][16];
    __shared__ int   ri[FPT][16];
    __shared__ int   zo[FPT];

    const int tid = threadIdx.x;
    const int tx = tid & 15, ty = tid >> 4;
    const int tot = *flagcnt;
    const int kt = blockIdx.y * 64;

    for (int cbk = blockIdx.x; cbk * FPT < tot; cbk += gridDim.x) {
        const int base = cbk * FPT;
        const int cnt = min(FPT, tot - base);
        __syncthreads();
        if (tid < FPT) {
            int n = flaglist[base + ((tid < cnt) ? tid : 0)];
            zo[tid] = (n >> 12) * DD * HWS + (n & 4095);
        }
        __syncthreads();

        float acc[4][4] = {};
        for (int dc = 0; dc < DD; dc += 64) {
            #pragma unroll
            for (int i = 0; i < 16; ++i) {
                int li = tid + i * 256;
                int d = li >> 6, pp = li & 63;
                As[d][pp] = z_e[(size_t)zo[pp] + (size_t)(dc + d) * HWS];
            }
            #pragma unroll
            for (int i = 0; i < 16; ++i) {
                int li = tid + i * 256;
                int k = li >> 6, d = li & 63;
                Bs[d][k] = cb[(size_t)(kt + k) * DD + dc + d];
            }
            __syncthreads();
            #pragma unroll
            for (int d = 0; d < 64; ++d) {
                const float4 a4 = *reinterpret_cast<const float4*>(&As[d][ty * 4]);
                const float4 b4 = *reinterpret_cast<const float4*>(&Bs[d][tx * 4]);
                const float a[4] = {a4.x, a4.y, a4.z, a4.w};
                const float bb[4] = {b4.x, b4.y, b4.z, b4.w};
                #pragma unroll
                for (int j = 0; j < 4; ++j)
                    #pragma unroll
                    for (int i = 0; i < 4; ++i)
                        acc[j][i] = fmaf(a[j], bb[i], acc[j][i]);
            }
            __syncthreads();
        }

        float bestv[4]; int besti[4];
        #pragma unroll
        for (int j = 0; j < 4; ++j) { bestv[j] = 3.4e38f; besti[j] = 0; }
        #pragma unroll
        for (int i = 0; i < 4; ++i) {
            int k = kt + tx * 4 + i;
            float c = cnorm[k];
            #pragma unroll
            for (int j = 0; j < 4; ++j) {
                float dist = c - 2.0f * acc[j][i];
                if (dist < bestv[j]) { bestv[j] = dist; besti[j] = k; }
            }
        }
        #pragma unroll
        for (int j = 0; j < 4; ++j) { rv[ty * 4 + j][tx] = bestv[j]; ri[ty * 4 + j][tx] = besti[j]; }
        __syncthreads();

        if (tid < cnt) {
            float bv = rv[tid][0]; int bi = ri[tid][0];
            #pragma unroll
            for (int t = 1; t < 16; ++t) {
                float v = rv[tid][t]; int i2 = ri[tid][t];
                if (v < bv || (v == bv && i2 < bi)) { bv = v; bi = i2; }
            }
            unsigned uv = __float_as_uint(bv);
            uv = (uv & 0x80000000u) ? ~uv : (uv | 0x80000000u);
            unsigned long long key = ((unsigned long long)uv << 32) | (unsigned)bi;
            atomicMin(&fixmin[base + tid], key);
        }
    }
}

// ---------------------------------------------------------------------------
// scan_apply: phase 1 (single block) applies fixup winners + corrects cnti;
// phase 2 exclusive-scans cnti into start/cursor.
__global__ __launch_bounds__(256) void scan_apply_kernel(const int* __restrict__ flagcnt,
                                                         const int* __restrict__ flaglist,
                                                         const unsigned long long* __restrict__ fixmin,
                                                         int* __restrict__ idx_out,
                                                         int* __restrict__ cnti,
                                                         int* __restrict__ start,
                                                         int* __restrict__ cursor) {
    const int t = threadIdx.x;
    const int tot = *flagcnt;
    for (int f = t; f < tot; f += 256) {
        int n = flaglist[f];
        int nk = (int)(fixmin[f] & 0xFFFFFFFFull);
        int ok = idx_out[n];
        if (nk != ok) {
            atomicSub(&cnti[ok], 1);
            atomicAdd(&cnti[nk], 1);
            idx_out[n] = nk;
        }
    }
    __syncthreads();

    __shared__ int ps[256];
    int v[8], s = 0;
    #pragma unroll
    for (int j = 0; j < 8; ++j) { v[j] = cnti[t * 8 + j]; s += v[j]; }
    ps[t] = s;
    __syncthreads();
    for (int off = 1; off < 256; off <<= 1) {
        int x = (t >= off) ? ps[t - off] : 0;
        __syncthreads();
        ps[t] += x;
        __syncthreads();
    }
    int base = ps[t] - s;
    #pragma unroll
    for (int j = 0; j < 8; ++j) { start[t * 8 + j] = base; cursor[t * 8 + j] = base; base += v[j]; }
}

// ---------------------------------------------------------------------------
// fp32 argmin (fallback tier)
#define PT 64
#define KT 64
#define DC 64
__global__ __launch_bounds__(256) void argmin_kernel(const float* __restrict__ z_e,
                                                     const float* __restrict__ cb,
                                                     const float* __restrict__ cnorm,
                                                     int* __restrict__ idx_out) {
    __shared__ float As[DC][PT + 4];
    __shared__ float Bs[DC][KT + 4];
    __shared__ float rv[PT][16];
    __shared__ int   ri[PT][16];
    const int tid = threadIdx.x;
    const int tx = tid & 15, ty = tid >> 4;
    const int n0 = blockIdx.x * PT;
    const int b = n0 >> 12;
    const int hw0 = n0 & 4095;
    const float* zb = z_e + (size_t)b * DD * HWS + hw0;
    float bestv[4]; int besti[4];
    #pragma unroll
    for (int j = 0; j < 4; ++j) { bestv[j] = 3.4e38f; besti[j] = 0; }
    for (int kt = 0; kt < KC; kt += KT) {
        float acc[4][4] = {};
        for (int dc = 0; dc < DD; dc += DC) {
            #pragma unroll
            for (int i = 0; i < 16; ++i) {
                int li = tid + i * 256;
                int d = li >> 6, pp = li & 63;
                As[d][pp] = zb[(size_t)(dc + d) * HWS + pp];
            }
            #pragma unroll
            for (int i = 0; i < 16; ++i) {
                int li = tid + i * 256;
                int k = li >> 6, d = li & 63;
                Bs[d][k] = cb[(size_t)(kt + k) * DD + dc + d];
            }
            __syncthreads();
            #pragma unroll
            for (int d = 0; d < DC; ++d) {
                const float4 a4 = *reinterpret_cast<const float4*>(&As[d][ty * 4]);
                const float4 b4 = *reinterpret_cast<const float4*>(&Bs[d][tx * 4]);
                const float a[4] = {a4.x, a4.y, a4.z, a4.w};
                const float bb[4] = {b4.x, b4.y, b4.z, b4.w};
                #pragma unroll
                for (int j = 0; j < 4; ++j)
                    #pragma unroll
                    for (int i = 0; i < 4; ++i)
                        acc[j][i] = fmaf(a[j], bb[i], acc[j][i]);
            }
            __syncthreads();
        }
        #pragma unroll
        for (int i = 0; i < 4; ++i) {
            int k = kt + tx * 4 + i;
            float c = cnorm[k];
            #pragma unroll
            for (int j = 0; j < 4; ++j) {
                float dist = c - 2.0f * acc[j][i];
                if (dist < bestv[j]) { bestv[j] = dist; besti[j] = k; }
            }
        }
    }
    #pragma unroll
    for (int j = 0; j < 4; ++j) { rv[ty * 4 + j][tx] = bestv[j]; ri[ty * 4 + j][tx] = besti[j]; }
    __syncthreads();
    if (tid < PT) {
        float bv = rv[tid][0]; int bi = ri[tid][0];
        #pragma unroll
        for (int t = 1; t < 16; ++t) {
            float v = rv[tid][t]; int i2 = ri[tid][t];
            if (v < bv || (v == bv && i2 < bi)) { bv = v; bi = i2; }
        }
        idx_out[n0 + tid] = bi;
    }
}

__global__ __launch_bounds__(256) void hist_kernel(const int* __restrict__ idx,
                                                   int* __restrict__ cnti) {
    int n = blockIdx.x * 256 + threadIdx.x;
    atomicAdd(&cnti[idx[n]], 1);
}

// standalone scatter (mid tier)
__global__ __launch_bounds__(256) void scatter_ids_kernel(const int* __restrict__ idx,
                                                          int* __restrict__ cursor,
                                                          int* __restrict__ sorted,
                                                          float* __restrict__ out_idxf) {
    int n = blockIdx.x * 256 + threadIdx.x;
    int k = idx[n];
    out_idxf[n] = (float)k;
    int pos = atomicAdd(&cursor[k], 1);
    sorted[pos] = n;
}

// ---------------------------------------------------------------------------
// Balanced segment sum: 32 sorted points per block (grid 2048).
__global__ __launch_bounds__(256) void dw_chunk_kernel(const unsigned short* __restrict__ zh,
                                                       const unsigned short* __restrict__ zl,
                                                       const int* __restrict__ sorted,
                                                       const int* __restrict__ idx,
                                                       float* __restrict__ dwacc) {
    const int t = threadIdx.x;
    const int base = blockIdx.x * CHPTS;
    int kcur = idx[sorted[base]];
    float acc = 0.f;
    for (int i = 0; i < CHPTS; ++i) {
        const int n = sorted[base + i];
        const int k = idx[n];
        if (k != kcur) {
            atomicAdd(&dwacc[(size_t)kcur * DD + t], acc);
            acc = 0.f; kcur = k;
        }
        acc += bf2f(zh[(size_t)n * DD + t]) + bf2f(zl[(size_t)n * DD + t]);
    }
    atomicAdd(&dwacc[(size_t)kcur * DD + t], acc);
}

// Fallback: strided z_e reads, per-code blocks (mid tier only)
__global__ __launch_bounds__(256) void dw_direct_kernel(const float* __restrict__ z_e,
                                                        const int* __restrict__ sorted,
                                                        const int* __restrict__ start,
                                                        const int* __restrict__ cnti,
                                                        float* __restrict__ part) {
    const int k = blockIdx.x, c = blockIdx.y, t = threadIdx.x;
    const int s0 = start[k], cnt = cnti[k];
    float acc = 0.f;
    for (int p = c; p < cnt; p += NCH) {
        int n = sorted[s0 + p];
        int b = n >> 12, hw = n & 4095;
        acc += z_e[(size_t)b * DD * HWS + (size_t)t * HWS + hw];
    }
    part[((size_t)k * NCH + c) * DD + t] = acc;
}

// ---------------------------------------------------------------------------
// z_q + straight-through + loss partials (16 elems/thread). fuse_tail=1:
// blocks 0..255 additionally scatter point ids + zero dwacc (runs after scan).
__global__ __launch_bounds__(256) void zq_scatter_kernel(const float* __restrict__ z_e,
                                                         const float* __restrict__ cb,
                                                         const int* __restrict__ idx,
                                                         float* __restrict__ out_zq,
                                                         float* __restrict__ lossp,
                                                         int* __restrict__ cursor,
                                                         int* __restrict__ sorted,
                                                         float* __restrict__ out_idxf,
                                                         float* __restrict__ dwacc,
                                                         int fuse_tail) {
    const int tid = threadIdx.x;
    const size_t base = ((size_t)blockIdx.x * 256 + tid) * 16;
    const int hw = (int)(base & 4095);
    const int d = (int)((base >> 12) & 255);
    const int b = (int)(base >> 20);
    const int n0 = b * HWS + hw;

    const int4* ip = reinterpret_cast<const int4*>(idx + n0);
    const float4* zp = reinterpret_cast<const float4*>(z_e + base);
    float4* op = reinterpret_cast<float4*>(out_zq + base);

    float ls = 0.f;
    #pragma unroll
    for (int g = 0; g < 4; ++g) {
        int4 i4 = ip[g];
        float4 z4 = zp[g];
        int kk[4] = {i4.x, i4.y, i4.z, i4.w};
        float zz[4] = {z4.x, z4.y, z4.z, z4.w};
        float o4[4];
        #pragma unroll
        for (int q = 0; q < 4; ++q) {
            float qv = cb[(size_t)kk[q] * DD + d];
            o4[q] = zz[q] + (qv - zz[q]);
            float df = zz[q] - qv;
            ls += df * df;
        }
        float4 w4; w4.x = o4[0]; w4.y = o4[1]; w4.z = o4[2]; w4.w = o4[3];
        op[g] = w4;
    }

    #pragma unroll
    for (int off = 32; off > 0; off >>= 1) ls += __shfl_down(ls, off, 64);
    __shared__ float wsum[4];
    if ((tid & 63) == 0) wsum[tid >> 6] = ls;
    __syncthreads();
    if (tid == 0) lossp[blockIdx.x] = wsum[0] + wsum[1] + wsum[2] + wsum[3];

    if (fuse_tail && blockIdx.x < 256) {
        int n = blockIdx.x * 256 + tid;
        int k = idx[n];
        out_idxf[n] = (float)k;
        int pos = atomicAdd(&cursor[k], 1);
        sorted[pos] = n;
        #pragma unroll
        for (int i = 0; i < (KC * DD) / NPTS; ++i)   // 8 floats/thread -> 2 MB total
            dwacc[n + i * NPTS] = 0.f;
    }
}

// ---------------------------------------------------------------------------
// EMA finalize (+ block 0 reduces the loss partials).
__global__ __launch_bounds__(256) void finalize_dw_kernel(const float* __restrict__ ema_count,
                                                          const float* __restrict__ ema_weight,
                                                          const int* __restrict__ cnti,
                                                          const float* __restrict__ dwacc,
                                                          const float* __restrict__ lossp,
                                                          float* __restrict__ out_cb,
                                                          float* __restrict__ out_cnt,
                                                          float* __restrict__ out_w,
                                                          float* __restrict__ out_loss) {
    const int t = blockIdx.x * 256 + threadIdx.x;
    const int k = t >> 8, d = t & 255;
    const float nc = ema_count[k] * DECAYF + ONEMD * (float)cnti[k];
    const float nw = ema_weight[t] * DECAYF + ONEMD * dwacc[t];
    out_w[t] = nw;
    out_cb[t] = nw / (nc + EPSF);
    if (d == 0) out_cnt[k] = nc;

    if (blockIdx.x == 0) {
        __shared__ double sd[256];
        const int tid = threadIdx.x;
        double s = 0.0;
        for (int i = tid; i < NLOSS; i += 256) s += (double)lossp[i];
        sd[tid] = s;
        __syncthreads();
        for (int off = 128; off > 0; off >>= 1) {
            if (tid < off) sd[tid] += sd[tid + off];
            __syncthreads();
        }
        if (tid == 0) out_loss[0] = (float)(sd[0] / 16777216.0);
    }
}

__global__ __launch_bounds__(256) void finalize_part_kernel(const float* __restrict__ ema_count,
                                                            const float* __restrict__ ema_weight,
                                                            const int* __restrict__ cnti,
                                                            const float* __restrict__ part,
                                                            const float* __restrict__ lossp,
                                                            float* __restrict__ out_cb,
                                                            float* __restrict__ out_cnt,
                                                            float* __restrict__ out_w,
                                                            float* __restrict__ out_loss) {
    const int t = blockIdx.x * 256 + threadIdx.x;
    const int k = t >> 8, d = t & 255;
    float dw = 0.f;
    #pragma unroll
    for (int c = 0; c < NCH; ++c) dw += part[((size_t)k * NCH + c) * DD + d];
    const float nc = ema_count[k] * DECAYF + ONEMD * (float)cnti[k];
    const float nw = ema_weight[t] * DECAYF + ONEMD * dw;
    out_w[t] = nw;
    out_cb[t] = nw / (nc + EPSF);
    if (d == 0) out_cnt[k] = nc;

    if (blockIdx.x == 0) {
        __shared__ double sd[256];
        const int tid = threadIdx.x;
        double s = 0.0;
        for (int i = tid; i < NLOSS; i += 256) s += (double)lossp[i];
        sd[tid] = s;
        __syncthreads();
        for (int off = 128; off > 0; off >>= 1) {
            if (tid < off) sd[tid] += sd[tid + off];
            __syncthreads();
        }
        if (tid == 0) out_loss[0] = (float)(sd[0] / 16777216.0);
    }
}

// ---------------------------------------------------------------------------
extern "C" void kernel_launch(void* const* d_in, const int* in_sizes, int n_in,
                              void* d_out, int out_size, void* d_ws, size_t ws_size,
                              hipStream_t stream) {
    const float* z_e       = (const float*)d_in[0];
    const float* codebook  = (const float*)d_in[1];
    const float* ema_count = (const float*)d_in[2];
    const float* ema_weight= (const float*)d_in[3];
    float* out = (float*)d_out;
    char* ws = (char*)d_ws;

    int*   ws_idx    = (int*)(ws + WS_IDX);
    int*   ws_sorted = (int*)(ws + WS_SORTED);
    int*   ws_cnti   = (int*)(ws + WS_CNTI);
    int*   ws_start  = (int*)(ws + WS_START);
    int*   ws_cursor = (int*)(ws + WS_CURSOR);
    int*   ws_flagc  = (int*)(ws + WS_FLAGCNT);
    int*   ws_flags  = (int*)(ws + WS_FLAGS);
    float* ws_lossp  = (float*)(ws + WS_LOSSP);
    float* ws_cnorm  = (float*)(ws + WS_CNORM);
    unsigned long long* ws_fixmin = (unsigned long long*)(ws + WS_PART);
    float* ws_dwacc  = (float*)(ws + WS_PART);
    float* ws_part   = (float*)(ws + WS_PART);
    float4* ws_half  = (float4*)(ws + WS_HALF);
    unsigned short* ws_cbh = (unsigned short*)(ws + WS_CBH);
    unsigned short* ws_cbl = (unsigned short*)(ws + WS_CBL);
    unsigned short* ws_zh  = (unsigned short*)(ws + WS_ZH);
    unsigned short* ws_zl  = (unsigned short*)(ws + WS_ZL);

    const bool mfma_path = (ws_size >= WS_NEED_MFMA);
    const bool mid_path  = (ws_size >= WS_NEED_MID);

    if (mfma_path) {
        prep_kernel<<<4104, 256, 0, stream>>>(z_e, codebook, ws_cnorm, ws_cbh, ws_cbl,
                                              ws_zh, ws_zl, ws_cnti, ws_flagc);
        argmin_mfma_kernel<<<dim3(NPTS / 128, 2), 256, 0, stream>>>(ws_zh, ws_zl,
                                                                    ws_cbh, ws_cbl,
                                                                    ws_cnorm, ws_half);
        merge_kernel<<<NPTS / 256, 256, 0, stream>>>(ws_half, ws_idx, ws_cnti,
                                                     ws_flagc, ws_flags, ws_fixmin);
        fixup_part_kernel<<<dim3(128, KC / 64), 256, 0, stream>>>(z_e, codebook, ws_cnorm,
                                                                  ws_flagc, ws_flags,
                                                                  ws_fixmin);
        scan_apply_kernel<<<1, 256, 0, stream>>>(ws_flagc, ws_flags, ws_fixmin,
                                                 ws_idx, ws_cnti, ws_start, ws_cursor);
        zq_scatter_kernel<<<NLOSS, 256, 0, stream>>>(z_e, codebook, ws_idx,
                                                     out + OUT_ZQ, ws_lossp,
                                                     ws_cursor, ws_sorted,
                                                     out + OUT_IDX, ws_dwacc, 1);
        dw_chunk_kernel<<<NPTS / CHPTS, 256, 0, stream>>>(ws_zh, ws_zl, ws_sorted,
                                                          ws_idx, ws_dwacc);
        finalize_dw_kernel<<<(KC * DD) / 256, 256, 0, stream>>>(ema_count, ema_weight,
                                                                ws_cnti, ws_dwacc, ws_lossp,
                                                                out + OUT_CB, out + OUT_CNT,
                                                                out + OUT_W, out + OUT_LOSS);
    } else if (mid_path) {
        hipMemsetAsync(ws + WS_CNTI, 0, (size_t)(WS_FLAGCNT + 256 - WS_CNTI), stream);
        cnorm_kernel<<<(KC + 255) / 256, 256, 0, stream>>>(codebook, ws_cnorm);
        argmin_kernel<<<NPTS / PT, 256, 0, stream>>>(z_e, codebook, ws_cnorm, ws_idx);
        hist_kernel<<<NPTS / 256, 256, 0, stream>>>(ws_idx, ws_cnti);
        scan_apply_kernel<<<1, 256, 0, stream>>>(ws_flagc, ws_flags, ws_fixmin,
                                                 ws_idx, ws_cnti, ws_start, ws_cursor);
        zq_scatter_kernel<<<NLOSS, 256, 0, stream>>>(z_e, codebook, ws_idx,
                                                     out + OUT_ZQ, ws_lossp,
                                                     ws_cursor, ws_sorted,
                                                     out + OUT_IDX, ws_part, 0);
        scatter_ids_kernel<<<NPTS / 256, 256, 0, stream>>>(ws_idx, ws_cursor, ws_sorted,
                                                           out + OUT_IDX);
        dw_direct_kernel<<<dim3(KC, NCH), 256, 0, stream>>>(z_e, ws_sorted,
                                                            ws_start, ws_cnti, ws_part + KC * DD);
        finalize_part_kernel<<<(KC * DD) / 256, 256, 0, stream>>>(ema_count, ema_weight,
                                                                  ws_cnti, ws_part + KC * DD,
                                                                  ws_lossp,
                                                                  out + OUT_CB, out + OUT_CNT,
                                                                  out + OUT_W, out + OUT_LOSS);
    }
}

// Round 17
// 403.352 us; speedup vs baseline: 1.0685x; 1.0685x over previous
//
#include <hip/hip_runtime.h>
#include <hip/hip_bf16.h>

// VQ-VAE EMA vector quantizer, MI355X — round 17 (FINAL = r13 exact revert):
//  * r13 was the best passing configuration: 403.6us, absmax 752.
//  * argmin: r11's 3-chain hh/hl/lh MFMA, 64KB double-buffered LDS,
//    launch_bounds(256,2), 116 VGPR, fused epilogue (idx/hist/flag/fixmin).
//    ~195us — proven floor of this structure: five variants (dbuf 195,
//    ILP-dual 229, L2-direct 343, single-buf 199, K-split 196) all bracket it.
//  * 7-dispatch fused structure: prep / argmin / fixup grid-stride /
//    scan_apply / zq_scatter-tail / dw_chunk / finalize.
// Outputs (flat f32): z_q_st | idx-as-float | loss | new_codebook | new_ema_count | new_ema_weight

#define KC 2048
#define DD 256
#define NB 16
#define HWS 4096
#define NPTS 65536
#define DECAYF 0.99f
#define ONEMD 0.01f
#define EPSF 1e-5f
#define NCH 2
#define MARGIN 0.0625f
#define CHPTS 32
#define FPT 64
#define NLOSS 4096

typedef __attribute__((ext_vector_type(8))) short short8v;
typedef __attribute__((ext_vector_type(16))) float f32x16;

// ---- workspace layout (bytes) — identical to r7..r16 (74219776) ----
#define WS_IDX     0                          // int32 [65536]
#define WS_SORTED  262144                     // int32 [65536]
#define WS_CNTI    524288                     // int32 [2048]   (zeroed in prep)
#define WS_START   532480                     // int32 [2048]
#define WS_CURSOR  540672                     // int32 [2048]
#define WS_FLAGCNT 548864                     // int32 [1]      (zeroed in prep)
#define WS_FLAGS   549120                     // int32 [65536]
#define WS_LOSSP   549120                     // f32 [4096] overlay (written after flags dead)
#define WS_CNORM   811264                     // f32 [2048]
#define WS_PART    819456                     // fixmin u64[65536] (init in argmin) / dwacc f32[KC*DD] (zeroed in zq tail)
#define WS_CBH     5013760                    // bf16 [2048*256] fragment order, 1 MB
#define WS_CBL     6062336                    // bf16 [2048*256] fragment order, 1 MB
#define WS_ZH      7110912                    // bf16 [65536*256] 32 MB
#define WS_ZL      40665344                   // bf16 [65536*256] 32 MB
#define WS_NEED_MFMA 74219776ULL
#define WS_NEED_MID  5013760ULL

// ---- output offsets (floats) ----
#define OUT_ZQ   0
#define OUT_IDX  16777216
#define OUT_LOSS (OUT_IDX + NPTS)
#define OUT_CB   (OUT_LOSS + 1)
#define OUT_CNT  (OUT_CB + KC*DD)
#define OUT_W    (OUT_CNT + KC)

// ---------------------------------------------------------------------------
static __device__ __forceinline__ unsigned short f2bf_rn(float x) {
    unsigned u = __builtin_bit_cast(unsigned, x);
    unsigned r = (u + 0x7FFFu + ((u >> 16) & 1u)) >> 16;
    return (unsigned short)r;
}
static __device__ __forceinline__ float bf2f(unsigned short h) {
    unsigned u = ((unsigned)h) << 16;
    return __builtin_bit_cast(float, u);
}
static __device__ __forceinline__ void gload_lds16(const unsigned short* g,
                                                   unsigned short* l) {
    __builtin_amdgcn_global_load_lds(
        (const __attribute__((address_space(1))) void*)g,
        (__attribute__((address_space(3))) void*)l, 16, 0, 0);
}

// ---------------------------------------------------------------------------
// prep = transpose (blocks 0..4095) + cbsplit (blocks 4096..4103, zeroes
// cnti + flagcnt).
__global__ __launch_bounds__(256) void prep_kernel(const float* __restrict__ z_e,
                                                   const float* __restrict__ cb,
                                                   float* __restrict__ cnorm,
                                                   unsigned short* __restrict__ cbs_h,
                                                   unsigned short* __restrict__ cbs_l,
                                                   unsigned short* __restrict__ zh,
                                                   unsigned short* __restrict__ zl,
                                                   int* __restrict__ cnti,
                                                   int* __restrict__ flagcnt) {
    const int tid = threadIdx.x;
    if (blockIdx.x >= 4096) {
        int k = (blockIdx.x - 4096) * 256 + tid;
        cnti[k] = 0;
        if (k == 0) *flagcnt = 0;
        const int ct = k >> 5, lc = k & 31;
        const float4* row = reinterpret_cast<const float4*>(cb + (size_t)k * DD);
        float s = 0.f;
        #pragma unroll 4
        for (int chunk = 0; chunk < 32; ++chunk) {
            float4 v0 = row[chunk * 2], v1 = row[chunk * 2 + 1];
            float v[8] = {v0.x, v0.y, v0.z, v0.w, v1.x, v1.y, v1.z, v1.w};
            unsigned short hh[8], ll[8];
            #pragma unroll
            for (int j = 0; j < 8; ++j) {
                s += v[j] * v[j];
                hh[j] = f2bf_rn(v[j]);
                ll[j] = f2bf_rn(v[j] - bf2f(hh[j]));
            }
            const int ks = chunk >> 1, h = chunk & 1;
            size_t dst = (size_t)ct * 8192 + ks * 512 + (h * 32 + lc) * 8;
            *reinterpret_cast<ushort4*>(cbs_h + dst)     = *(ushort4*)&hh[0];
            *reinterpret_cast<ushort4*>(cbs_h + dst + 4) = *(ushort4*)&hh[4];
            *reinterpret_cast<ushort4*>(cbs_l + dst)     = *(ushort4*)&ll[0];
            *reinterpret_cast<ushort4*>(cbs_l + dst + 4) = *(ushort4*)&ll[4];
        }
        cnorm[k] = s;
        return;
    }
    __shared__ float t_lds[64][65];
    const int bid = blockIdx.x;
    const int hw0 = (bid & 63) * 64;
    const int d0 = ((bid >> 6) & 3) * 64;
    const int b = bid >> 8;
    const float* src = z_e + (size_t)b * DD * HWS;
    #pragma unroll
    for (int i = 0; i < 16; ++i) {
        int li = tid + i * 256;
        int d = li >> 6, hw = li & 63;
        t_lds[d][hw] = src[(size_t)(d0 + d) * HWS + hw0 + hw];
    }
    __syncthreads();
    #pragma unroll
    for (int i = 0; i < 16; ++i) {
        int li = tid + i * 256;
        int p = li >> 6, d = li & 63;
        float x = t_lds[d][p];
        unsigned short h = f2bf_rn(x);
        unsigned short l = f2bf_rn(x - bf2f(h));
        size_t o = ((size_t)b * HWS + hw0 + p) * DD + d0 + d;
        zh[o] = h; zl[o] = l;
    }
}

// fp32-cnorm only (fallback tier)
__global__ __launch_bounds__(256) void cnorm_kernel(const float* __restrict__ cb,
                                                    float* __restrict__ cnorm) {
    int k = blockIdx.x * 256 + threadIdx.x;
    if (k < KC) {
        const float4* row = reinterpret_cast<const float4*>(cb + (size_t)k * DD);
        float s = 0.f;
        #pragma unroll 8
        for (int i = 0; i < DD / 4; ++i) {
            float4 v = row[i];
            s += v.x * v.x + v.y * v.y + v.z * v.z + v.w * v.w;
        }
        cnorm[k] = s;
    }
}

// ---------------------------------------------------------------------------
// MFMA argmin (r11/r13 exact): block = 128 points (4 waves x 32). Codebook
// tile (32 codes, hi+lo, 32 KB) double-buffered in LDS via LINEAR
// global_load_lds; ds_read linear (conflict-free). 3 independent MFMA chains.
// Epilogue: idx + histogram + flag + fixmin init.
__global__ __launch_bounds__(256, 2) void argmin_mfma_kernel(const unsigned short* __restrict__ zh,
                                                             const unsigned short* __restrict__ zl,
                                                             const unsigned short* __restrict__ cbs_h,
                                                             const unsigned short* __restrict__ cbs_l,
                                                             const float* __restrict__ cnorm,
                                                             int* __restrict__ idx_out,
                                                             int* __restrict__ cnti,
                                                             int* __restrict__ flagcnt,
                                                             int* __restrict__ flaglist,
                                                             unsigned long long* __restrict__ fixmin) {
    __shared__ unsigned short lds_cb[2][2][16][512];   // [buf][hi/lo][ks][64 lanes * 8] = 64 KB

    const int tid = threadIdx.x;
    const int w = tid >> 6, lane = tid & 63;
    const int lc = lane & 31, h = lane >> 5;
    const int p = blockIdx.x * 128 + w * 32 + lc;

    const short8v* zhp = reinterpret_cast<const short8v*>(zh + (size_t)p * DD + h * 8);
    const short8v* zlp = reinterpret_cast<const short8v*>(zl + (size_t)p * DD + h * 8);
    short8v bh[16], bl[16];
    #pragma unroll
    for (int ks = 0; ks < 16; ++ks) { bh[ks] = zhp[ks * 2]; bl[ks] = zlp[ks * 2]; }

    auto stage = [&](int ct, int buf) {
        #pragma unroll
        for (int j = 0; j < 8; ++j) {
            const int inst = w * 8 + j;          // 0..31
            const int part = inst >> 4;          // 0=hi 1=lo
            const int ks = inst & 15;
            const unsigned short* src =
                (part ? cbs_l : cbs_h) + (size_t)ct * 8192 + ks * 512 + lane * 8;
            gload_lds16(src, &lds_cb[buf][part][ks][0]);
        }
    };

    float bv1 = 3.4e38f, bv2 = 3.4e38f;
    int bi1 = 0;
    int cur = 0;

    stage(0, 0);
    __syncthreads();

    for (int ct = 0; ct < KC / 32; ++ct) {
        if (ct + 1 < KC / 32) stage(ct + 1, cur ^ 1);

        f32x16 a0, a1, a2;
        #pragma unroll
        for (int i = 0; i < 16; ++i) { a0[i] = 0.f; a1[i] = 0.f; a2[i] = 0.f; }
        #pragma unroll
        for (int ks = 0; ks < 16; ++ks) {
            short8v ah = *reinterpret_cast<const short8v*>(&lds_cb[cur][0][ks][lane * 8]);
            short8v al = *reinterpret_cast<const short8v*>(&lds_cb[cur][1][ks][lane * 8]);
            a0 = __builtin_amdgcn_mfma_f32_32x32x16_bf16(ah, bh[ks], a0, 0, 0, 0);
            a1 = __builtin_amdgcn_mfma_f32_32x32x16_bf16(ah, bl[ks], a1, 0, 0, 0);
            a2 = __builtin_amdgcn_mfma_f32_32x32x16_bf16(al, bh[ks], a2, 0, 0, 0);
        }
        // C layout (32x32): point = lane&31, code_row = (reg&3) + 8*(reg>>2) + 4*h
        const float* cnb = cnorm + ct * 32 + h * 4;
        #pragma unroll
        for (int g = 0; g < 4; ++g) {
            float4 cn = *reinterpret_cast<const float4*>(cnb + g * 8);
            float cna[4] = {cn.x, cn.y, cn.z, cn.w};
            #pragma unroll
            for (int q = 0; q < 4; ++q) {
                float dot = a0[g * 4 + q] + a1[g * 4 + q] + a2[g * 4 + q];
                float v = fmaf(dot, -2.0f, cna[q]);
                int k = ct * 32 + g * 8 + h * 4 + q;
                bool lt = v < bv1;
                bv2 = fminf(bv2, fmaxf(v, bv1));
                bv1 = fminf(bv1, v);
                bi1 = lt ? k : bi1;
            }
        }
        __syncthreads();
        cur ^= 1;
    }

    float ov1 = __shfl_xor(bv1, 32, 64);
    float ov2 = __shfl_xor(bv2, 32, 64);
    int   oi1 = __shfl_xor(bi1, 32, 64);
    float nv1 = fminf(bv1, ov1);
    float nv2 = fminf(fmaxf(bv1, ov1), fminf(bv2, ov2));
    int ni1 = (ov1 < bv1 || (ov1 == bv1 && oi1 < bi1)) ? oi1 : bi1;

    if (h == 0) {
        idx_out[p] = ni1;
        atomicAdd(&cnti[ni1], 1);                 // histogram (scan_apply corrects flips)
        if (nv2 - nv1 < MARGIN) {
            int pos = atomicAdd(flagcnt, 1);
            flaglist[pos] = p;
            fixmin[pos] = ~0ULL;                  // +inf key (replaces memset)
        }
    }
}

// ---------------------------------------------------------------------------
// fixup stage 1: grid-stride (x over 64-point chunks, y over 64-code tiles);
// exact fp32; packed u64 atomicMin == exact first-min semantics.
__global__ __launch_bounds__(256) void fixup_part_kernel(const float* __restrict__ z_e,
                                                         const float* __restrict__ cb,
                                                         const float* __restrict__ cnorm,
                                                         const int* __restrict__ flagcnt,
                                                         const int* __restrict__ flaglist,
                                                         unsigned long long* __restrict__ fixmin) {
    __shared__ float As[64][FPT + 4];
    __shared__ float Bs[64][64 + 4];
    __shared__ float rv[FPT][16];
    __shared__ int   ri[FPT][16];
    __shared__ int   zo[FPT];

    const int tid = threadIdx.x;
    const int tx = tid & 15, ty = tid >> 4;
    const int tot = *flagcnt;
    const int kt = blockIdx.y * 64;

    for (int cbk = blockIdx.x; cbk * FPT < tot; cbk += gridDim.x) {
        const int base = cbk * FPT;
        const int cnt = min(FPT, tot - base);
        __syncthreads();
        if (tid < FPT) {
            int n = flaglist[base + ((tid < cnt) ? tid : 0)];
            zo[tid] = (n >> 12) * DD * HWS + (n & 4095);
        }
        __syncthreads();

        float acc[4][4] = {};
        for (int dc = 0; dc < DD; dc += 64) {
            #pragma unroll
            for (int i = 0; i < 16; ++i) {
                int li = tid + i * 256;
                int d = li >> 6, pp = li & 63;
                As[d][pp] = z_e[(size_t)zo[pp] + (size_t)(dc + d) * HWS];
            }
            #pragma unroll
            for (int i = 0; i < 16; ++i) {
                int li = tid + i * 256;
                int k = li >> 6, d = li & 63;
                Bs[d][k] = cb[(size_t)(kt + k) * DD + dc + d];
            }
            __syncthreads();
            #pragma unroll
            for (int d = 0; d < 64; ++d) {
                const float4 a4 = *reinterpret_cast<const float4*>(&As[d][ty * 4]);
                const float4 b4 = *reinterpret_cast<const float4*>(&Bs[d][tx * 4]);
                const float a[4] = {a4.x, a4.y, a4.z, a4.w};
                const float bb[4] = {b4.x, b4.y, b4.z, b4.w};
                #pragma unroll
                for (int j = 0; j < 4; ++j)
                    #pragma unroll
                    for (int i = 0; i < 4; ++i)
                        acc[j][i] = fmaf(a[j], bb[i], acc[j][i]);
            }
            __syncthreads();
        }

        float bestv[4]; int besti[4];
        #pragma unroll
        for (int j = 0; j < 4; ++j) { bestv[j] = 3.4e38f; besti[j] = 0; }
        #pragma unroll
        for (int i = 0; i < 4; ++i) {
            int k = kt + tx * 4 + i;
            float c = cnorm[k];
            #pragma unroll
            for (int j = 0; j < 4; ++j) {
                float dist = c - 2.0f * acc[j][i];
                if (dist < bestv[j]) { bestv[j] = dist; besti[j] = k; }
            }
        }
        #pragma unroll
        for (int j = 0; j < 4; ++j) { rv[ty * 4 + j][tx] = bestv[j]; ri[ty * 4 + j][tx] = besti[j]; }
        __syncthreads();

        if (tid < cnt) {
            float bv = rv[tid][0]; int bi = ri[tid][0];
            #pragma unroll
            for (int t = 1; t < 16; ++t) {
                float v = rv[tid][t]; int i2 = ri[tid][t];
                if (v < bv || (v == bv && i2 < bi)) { bv = v; bi = i2; }
            }
            unsigned uv = __float_as_uint(bv);
            uv = (uv & 0x80000000u) ? ~uv : (uv | 0x80000000u);
            unsigned long long key = ((unsigned long long)uv << 32) | (unsigned)bi;
            atomicMin(&fixmin[base + tid], key);
        }
    }
}

// ---------------------------------------------------------------------------
// scan_apply: phase 1 (single block) applies fixup winners + corrects cnti;
// phase 2 exclusive-scans cnti into start/cursor.
__global__ __launch_bounds__(256) void scan_apply_kernel(const int* __restrict__ flagcnt,
                                                         const int* __restrict__ flaglist,
                                                         const unsigned long long* __restrict__ fixmin,
                                                         int* __restrict__ idx_out,
                                                         int* __restrict__ cnti,
                                                         int* __restrict__ start,
                                                         int* __restrict__ cursor) {
    const int t = threadIdx.x;
    const int tot = *flagcnt;
    for (int f = t; f < tot; f += 256) {
        int n = flaglist[f];
        int nk = (int)(fixmin[f] & 0xFFFFFFFFull);
        int ok = idx_out[n];
        if (nk != ok) {
            atomicSub(&cnti[ok], 1);
            atomicAdd(&cnti[nk], 1);
            idx_out[n] = nk;
        }
    }
    __syncthreads();

    __shared__ int ps[256];
    int v[8], s = 0;
    #pragma unroll
    for (int j = 0; j < 8; ++j) { v[j] = cnti[t * 8 + j]; s += v[j]; }
    ps[t] = s;
    __syncthreads();
    for (int off = 1; off < 256; off <<= 1) {
        int x = (t >= off) ? ps[t - off] : 0;
        __syncthreads();
        ps[t] += x;
        __syncthreads();
    }
    int base = ps[t] - s;
    #pragma unroll
    for (int j = 0; j < 8; ++j) { start[t * 8 + j] = base; cursor[t * 8 + j] = base; base += v[j]; }
}

// ---------------------------------------------------------------------------
// fp32 argmin (fallback tier)
#define PT 64
#define KT 64
#define DC 64
__global__ __launch_bounds__(256) void argmin_kernel(const float* __restrict__ z_e,
                                                     const float* __restrict__ cb,
                                                     const float* __restrict__ cnorm,
                                                     int* __restrict__ idx_out) {
    __shared__ float As[DC][PT + 4];
    __shared__ float Bs[DC][KT + 4];
    __shared__ float rv[PT][16];
    __shared__ int   ri[PT][16];
    const int tid = threadIdx.x;
    const int tx = tid & 15, ty = tid >> 4;
    const int n0 = blockIdx.x * PT;
    const int b = n0 >> 12;
    const int hw0 = n0 & 4095;
    const float* zb = z_e + (size_t)b * DD * HWS + hw0;
    float bestv[4]; int besti[4];
    #pragma unroll
    for (int j = 0; j < 4; ++j) { bestv[j] = 3.4e38f; besti[j] = 0; }
    for (int kt = 0; kt < KC; kt += KT) {
        float acc[4][4] = {};
        for (int dc = 0; dc < DD; dc += DC) {
            #pragma unroll
            for (int i = 0; i < 16; ++i) {
                int li = tid + i * 256;
                int d = li >> 6, pp = li & 63;
                As[d][pp] = zb[(size_t)(dc + d) * HWS + pp];
            }
            #pragma unroll
            for (int i = 0; i < 16; ++i) {
                int li = tid + i * 256;
                int k = li >> 6, d = li & 63;
                Bs[d][k] = cb[(size_t)(kt + k) * DD + dc + d];
            }
            __syncthreads();
            #pragma unroll
            for (int d = 0; d < DC; ++d) {
                const float4 a4 = *reinterpret_cast<const float4*>(&As[d][ty * 4]);
                const float4 b4 = *reinterpret_cast<const float4*>(&Bs[d][tx * 4]);
                const float a[4] = {a4.x, a4.y, a4.z, a4.w};
                const float bb[4] = {b4.x, b4.y, b4.z, b4.w};
                #pragma unroll
                for (int j = 0; j < 4; ++j)
                    #pragma unroll
                    for (int i = 0; i < 4; ++i)
                        acc[j][i] = fmaf(a[j], bb[i], acc[j][i]);
            }
            __syncthreads();
        }
        #pragma unroll
        for (int i = 0; i < 4; ++i) {
            int k = kt + tx * 4 + i;
            float c = cnorm[k];
            #pragma unroll
            for (int j = 0; j < 4; ++j) {
                float dist = c - 2.0f * acc[j][i];
                if (dist < bestv[j]) { bestv[j] = dist; besti[j] = k; }
            }
        }
    }
    #pragma unroll
    for (int j = 0; j < 4; ++j) { rv[ty * 4 + j][tx] = bestv[j]; ri[ty * 4 + j][tx] = besti[j]; }
    __syncthreads();
    if (tid < PT) {
        float bv = rv[tid][0]; int bi = ri[tid][0];
        #pragma unroll
        for (int t = 1; t < 16; ++t) {
            float v = rv[tid][t]; int i2 = ri[tid][t];
            if (v < bv || (v == bv && i2 < bi)) { bv = v; bi = i2; }
        }
        idx_out[n0 + tid] = bi;
    }
}

__global__ __launch_bounds__(256) void hist_kernel(const int* __restrict__ idx,
                                                   int* __restrict__ cnti) {
    int n = blockIdx.x * 256 + threadIdx.x;
    atomicAdd(&cnti[idx[n]], 1);
}

// standalone scatter (mid tier)
__global__ __launch_bounds__(256) void scatter_ids_kernel(const int* __restrict__ idx,
                                                          int* __restrict__ cursor,
                                                          int* __restrict__ sorted,
                                                          float* __restrict__ out_idxf) {
    int n = blockIdx.x * 256 + threadIdx.x;
    int k = idx[n];
    out_idxf[n] = (float)k;
    int pos = atomicAdd(&cursor[k], 1);
    sorted[pos] = n;
}

// ---------------------------------------------------------------------------
// Balanced segment sum: 32 sorted points per block (grid 2048).
__global__ __launch_bounds__(256) void dw_chunk_kernel(const unsigned short* __restrict__ zh,
                                                       const unsigned short* __restrict__ zl,
                                                       const int* __restrict__ sorted,
                                                       const int* __restrict__ idx,
                                                       float* __restrict__ dwacc) {
    const int t = threadIdx.x;
    const int base = blockIdx.x * CHPTS;
    int kcur = idx[sorted[base]];
    float acc = 0.f;
    for (int i = 0; i < CHPTS; ++i) {
        const int n = sorted[base + i];
        const int k = idx[n];
        if (k != kcur) {
            atomicAdd(&dwacc[(size_t)kcur * DD + t], acc);
            acc = 0.f; kcur = k;
        }
        acc += bf2f(zh[(size_t)n * DD + t]) + bf2f(zl[(size_t)n * DD + t]);
    }
    atomicAdd(&dwacc[(size_t)kcur * DD + t], acc);
}

// Fallback: strided z_e reads, per-code blocks (mid tier only)
__global__ __launch_bounds__(256) void dw_direct_kernel(const float* __restrict__ z_e,
                                                        const int* __restrict__ sorted,
                                                        const int* __restrict__ start,
                                                        const int* __restrict__ cnti,
                                                        float* __restrict__ part) {
    const int k = blockIdx.x, c = blockIdx.y, t = threadIdx.x;
    const int s0 = start[k], cnt = cnti[k];
    float acc = 0.f;
    for (int p = c; p < cnt; p += NCH) {
        int n = sorted[s0 + p];
        int b = n >> 12, hw = n & 4095;
        acc += z_e[(size_t)b * DD * HWS + (size_t)t * HWS + hw];
    }
    part[((size_t)k * NCH + c) * DD + t] = acc;
}

// ---------------------------------------------------------------------------
// z_q + straight-through + loss partials (16 elems/thread). fuse_tail=1:
// blocks 0..255 additionally scatter point ids + zero dwacc (runs after scan).
__global__ __launch_bounds__(256) void zq_scatter_kernel(const float* __restrict__ z_e,
                                                         const float* __restrict__ cb,
                                                         const int* __restrict__ idx,
                                                         float* __restrict__ out_zq,
                                                         float* __restrict__ lossp,
                                                         int* __restrict__ cursor,
                                                         int* __restrict__ sorted,
                                                         float* __restrict__ out_idxf,
                                                         float* __restrict__ dwacc,
                                                         int fuse_tail) {
    const int tid = threadIdx.x;
    const size_t base = ((size_t)blockIdx.x * 256 + tid) * 16;
    const int hw = (int)(base & 4095);
    const int d = (int)((base >> 12) & 255);
    const int b = (int)(base >> 20);
    const int n0 = b * HWS + hw;

    const int4* ip = reinterpret_cast<const int4*>(idx + n0);
    const float4* zp = reinterpret_cast<const float4*>(z_e + base);
    float4* op = reinterpret_cast<float4*>(out_zq + base);

    float ls = 0.f;
    #pragma unroll
    for (int g = 0; g < 4; ++g) {
        int4 i4 = ip[g];
        float4 z4 = zp[g];
        int kk[4] = {i4.x, i4.y, i4.z, i4.w};
        float zz[4] = {z4.x, z4.y, z4.z, z4.w};
        float o4[4];
        #pragma unroll
        for (int q = 0; q < 4; ++q) {
            float qv = cb[(size_t)kk[q] * DD + d];
            o4[q] = zz[q] + (qv - zz[q]);
            float df = zz[q] - qv;
            ls += df * df;
        }
        float4 w4; w4.x = o4[0]; w4.y = o4[1]; w4.z = o4[2]; w4.w = o4[3];
        op[g] = w4;
    }

    #pragma unroll
    for (int off = 32; off > 0; off >>= 1) ls += __shfl_down(ls, off, 64);
    __shared__ float wsum[4];
    if ((tid & 63) == 0) wsum[tid >> 6] = ls;
    __syncthreads();
    if (tid == 0) lossp[blockIdx.x] = wsum[0] + wsum[1] + wsum[2] + wsum[3];

    if (fuse_tail && blockIdx.x < 256) {
        int n = blockIdx.x * 256 + tid;
        int k = idx[n];
        out_idxf[n] = (float)k;
        int pos = atomicAdd(&cursor[k], 1);
        sorted[pos] = n;
        #pragma unroll
        for (int i = 0; i < (KC * DD) / NPTS; ++i)   // 8 floats/thread -> 2 MB total
            dwacc[n + i * NPTS] = 0.f;
    }
}

// ---------------------------------------------------------------------------
// EMA finalize (+ block 0 reduces the loss partials).
__global__ __launch_bounds__(256) void finalize_dw_kernel(const float* __restrict__ ema_count,
                                                          const float* __restrict__ ema_weight,
                                                          const int* __restrict__ cnti,
                                                          const float* __restrict__ dwacc,
                                                          const float* __restrict__ lossp,
                                                          float* __restrict__ out_cb,
                                                          float* __restrict__ out_cnt,
                                                          float* __restrict__ out_w,
                                                          float* __restrict__ out_loss) {
    const int t = blockIdx.x * 256 + threadIdx.x;
    const int k = t >> 8, d = t & 255;
    const float nc = ema_count[k] * DECAYF + ONEMD * (float)cnti[k];
    const float nw = ema_weight[t] * DECAYF + ONEMD * dwacc[t];
    out_w[t] = nw;
    out_cb[t] = nw / (nc + EPSF);
    if (d == 0) out_cnt[k] = nc;

    if (blockIdx.x == 0) {
        __shared__ double sd[256];
        const int tid = threadIdx.x;
        double s = 0.0;
        for (int i = tid; i < NLOSS; i += 256) s += (double)lossp[i];
        sd[tid] = s;
        __syncthreads();
        for (int off = 128; off > 0; off >>= 1) {
            if (tid < off) sd[tid] += sd[tid + off];
            __syncthreads();
        }
        if (tid == 0) out_loss[0] = (float)(sd[0] / 16777216.0);
    }
}

__global__ __launch_bounds__(256) void finalize_part_kernel(const float* __restrict__ ema_count,
                                                            const float* __restrict__ ema_weight,
                                                            const int* __restrict__ cnti,
                                                            const float* __restrict__ part,
                                                            const float* __restrict__ lossp,
                                                            float* __restrict__ out_cb,
                                                            float* __restrict__ out_cnt,
                                                            float* __restrict__ out_w,
                                                            float* __restrict__ out_loss) {
    const int t = blockIdx.x * 256 + threadIdx.x;
    const int k = t >> 8, d = t & 255;
    float dw = 0.f;
    #pragma unroll
    for (int c = 0; c < NCH; ++c) dw += part[((size_t)k * NCH + c) * DD + d];
    const float nc = ema_count[k] * DECAYF + ONEMD * (float)cnti[k];
    const float nw = ema_weight[t] * DECAYF + ONEMD * dw;
    out_w[t] = nw;
    out_cb[t] = nw / (nc + EPSF);
    if (d == 0) out_cnt[k] = nc;

    if (blockIdx.x == 0) {
        __shared__ double sd[256];
        const int tid = threadIdx.x;
        double s = 0.0;
        for (int i = tid; i < NLOSS; i += 256) s += (double)lossp[i];
        sd[tid] = s;
        __syncthreads();
        for (int off = 128; off > 0; off >>= 1) {
            if (tid < off) sd[tid] += sd[tid + off];
            __syncthreads();
        }
        if (tid == 0) out_loss[0] = (float)(sd[0] / 16777216.0);
    }
}

// ---------------------------------------------------------------------------
extern "C" void kernel_launch(void* const* d_in, const int* in_sizes, int n_in,
                              void* d_out, int out_size, void* d_ws, size_t ws_size,
                              hipStream_t stream) {
    const float* z_e       = (const float*)d_in[0];
    const float* codebook  = (const float*)d_in[1];
    const float* ema_count = (const float*)d_in[2];
    const float* ema_weight= (const float*)d_in[3];
    float* out = (float*)d_out;
    char* ws = (char*)d_ws;

    int*   ws_idx    = (int*)(ws + WS_IDX);
    int*   ws_sorted = (int*)(ws + WS_SORTED);
    int*   ws_cnti   = (int*)(ws + WS_CNTI);
    int*   ws_start  = (int*)(ws + WS_START);
    int*   ws_cursor = (int*)(ws + WS_CURSOR);
    int*   ws_flagc  = (int*)(ws + WS_FLAGCNT);
    int*   ws_flags  = (int*)(ws + WS_FLAGS);
    float* ws_lossp  = (float*)(ws + WS_LOSSP);
    float* ws_cnorm  = (float*)(ws + WS_CNORM);
    unsigned long long* ws_fixmin = (unsigned long long*)(ws + WS_PART);
    float* ws_dwacc  = (float*)(ws + WS_PART);
    float* ws_part   = (float*)(ws + WS_PART);
    unsigned short* ws_cbh = (unsigned short*)(ws + WS_CBH);
    unsigned short* ws_cbl = (unsigned short*)(ws + WS_CBL);
    unsigned short* ws_zh  = (unsigned short*)(ws + WS_ZH);
    unsigned short* ws_zl  = (unsigned short*)(ws + WS_ZL);

    const bool mfma_path = (ws_size >= WS_NEED_MFMA);
    const bool mid_path  = (ws_size >= WS_NEED_MID);

    if (mfma_path) {
        prep_kernel<<<4104, 256, 0, stream>>>(z_e, codebook, ws_cnorm, ws_cbh, ws_cbl,
                                              ws_zh, ws_zl, ws_cnti, ws_flagc);
        argmin_mfma_kernel<<<NPTS / 128, 256, 0, stream>>>(ws_zh, ws_zl, ws_cbh, ws_cbl,
                                                           ws_cnorm, ws_idx, ws_cnti,
                                                           ws_flagc, ws_flags, ws_fixmin);
        fixup_part_kernel<<<dim3(128, KC / 64), 256, 0, stream>>>(z_e, codebook, ws_cnorm,
                                                                  ws_flagc, ws_flags,
                                                                  ws_fixmin);
        scan_apply_kernel<<<1, 256, 0, stream>>>(ws_flagc, ws_flags, ws_fixmin,
                                                 ws_idx, ws_cnti, ws_start, ws_cursor);
        zq_scatter_kernel<<<NLOSS, 256, 0, stream>>>(z_e, codebook, ws_idx,
                                                     out + OUT_ZQ, ws_lossp,
                                                     ws_cursor, ws_sorted,
                                                     out + OUT_IDX, ws_dwacc, 1);
        dw_chunk_kernel<<<NPTS / CHPTS, 256, 0, stream>>>(ws_zh, ws_zl, ws_sorted,
                                                          ws_idx, ws_dwacc);
        finalize_dw_kernel<<<(KC * DD) / 256, 256, 0, stream>>>(ema_count, ema_weight,
                                                                ws_cnti, ws_dwacc, ws_lossp,
                                                                out + OUT_CB, out + OUT_CNT,
                                                                out + OUT_W, out + OUT_LOSS);
    } else if (mid_path) {
        hipMemsetAsync(ws + WS_CNTI, 0, (size_t)(WS_FLAGCNT + 256 - WS_CNTI), stream);
        cnorm_kernel<<<(KC + 255) / 256, 256, 0, stream>>>(codebook, ws_cnorm);
        argmin_kernel<<<NPTS / PT, 256, 0, stream>>>(z_e, codebook, ws_cnorm, ws_idx);
        hist_kernel<<<NPTS / 256, 256, 0, stream>>>(ws_idx, ws_cnti);
        scan_apply_kernel<<<1, 256, 0, stream>>>(ws_flagc, ws_flags, ws_fixmin,
                                                 ws_idx, ws_cnti, ws_start, ws_cursor);
        zq_scatter_kernel<<<NLOSS, 256, 0, stream>>>(z_e, codebook, ws_idx,
                                                     out + OUT_ZQ, ws_lossp,
                                                     ws_cursor, ws_sorted,
                                                     out + OUT_IDX, ws_part, 0);
        scatter_ids_kernel<<<NPTS / 256, 256, 0, stream>>>(ws_idx, ws_cursor, ws_sorted,
                                                           out + OUT_IDX);
        dw_direct_kernel<<<dim3(KC, NCH), 256, 0, stream>>>(z_e, ws_sorted,
                                                            ws_start, ws_cnti, ws_part + KC * DD);
        finalize_part_kernel<<<(KC * DD) / 256, 256, 0, stream>>>(ema_count, ema_weight,
                                                                  ws_cnti, ws_part + KC * DD,
                                                                  ws_lossp,
                                                                  out + OUT_CB, out + OUT_CNT,
                                                                  out + OUT_W, out + OUT_LOSS);
    }
}